// Round 1
// 958.977 us; speedup vs baseline: 1.0851x; 1.0851x over previous
//
#include <hip/hip_runtime.h>
#include <hip/hip_bf16.h>
#include <cstdint>
#include <cstddef>

#define S 4096
#define D 2048
#define H 16
#define HD 128
#define F 8192

typedef unsigned short ushort_t;
typedef __attribute__((ext_vector_type(8))) short short8;
typedef __attribute__((ext_vector_type(4))) float floatx4;

__device__ __forceinline__ ushort_t f2bf(float f) {
  union { float f; unsigned u; } v; v.f = f;
  unsigned u = v.u;
  return (ushort_t)((u + 0x7fffu + ((u >> 16) & 1u)) >> 16);
}

__device__ __forceinline__ void async16(void* lds, const void* g) {
  __builtin_amdgcn_global_load_lds(
      (const __attribute__((address_space(1))) unsigned int*)g,
      (__attribute__((address_space(3))) unsigned int*)lds, 16, 0, 0);
}

template <int N>
__device__ __forceinline__ void vmcnt_() {
  static_assert(N >= 0 && N <= 4, "vmcnt range");
  if constexpr (N == 0) asm volatile("s_waitcnt vmcnt(0)" ::: "memory");
  else if constexpr (N == 1) asm volatile("s_waitcnt vmcnt(1)" ::: "memory");
  else if constexpr (N == 2) asm volatile("s_waitcnt vmcnt(2)" ::: "memory");
  else if constexpr (N == 3) asm volatile("s_waitcnt vmcnt(3)" ::: "memory");
  else asm volatile("s_waitcnt vmcnt(4)" ::: "memory");
}
__device__ __forceinline__ void bar_() { asm volatile("s_barrier" ::: "memory"); }

// ---------------------------------------------------------------- prep kernels

__global__ void cast_bf16(const float* __restrict__ src, ushort_t* __restrict__ dst, int n4) {
  int i = blockIdx.x * blockDim.x + threadIdx.x;
  if (i < n4) {
    float4 v = ((const float4*)src)[i];
    ushort4 o;
    o.x = f2bf(v.x); o.y = f2bf(v.y); o.z = f2bf(v.z); o.w = f2bf(v.w);
    ((ushort4*)dst)[i] = o;
  }
}

__global__ void build_bqkv(const float* __restrict__ bq, const float* __restrict__ bk,
                           const float* __restrict__ bv, float* __restrict__ bqkv) {
  int n = blockIdx.x * blockDim.x + threadIdx.x;
  if (n < 3 * D) {
    float v;
    if (n < D) v = bq[n];
    else if (n < 2 * D) v = bk[n - D];
    else v = bv[n - 2 * D];
    bqkv[n] = v;
  }
}

// dst[c][r] = src[r][c]; fp32 in, bf16 out. block (32,8)
__global__ void transpose_f32_bf16(const float* __restrict__ src, ushort_t* __restrict__ dst,
                                   int ldS, int ldD, long srcBatchStride, long dstBatchRows) {
  __shared__ float t[32][33];
  int b = blockIdx.z;
  src += (size_t)b * srcBatchStride;
  dst += (size_t)b * dstBatchRows * ldD;
  int r0 = blockIdx.x * 32, c0 = blockIdx.y * 32;
  int tx = threadIdx.x, ty = threadIdx.y;
#pragma unroll
  for (int i = 0; i < 4; ++i)
    t[ty + i * 8][tx] = src[(size_t)(r0 + ty + i * 8) * ldS + c0 + tx];
  __syncthreads();
#pragma unroll
  for (int i = 0; i < 4; ++i)
    dst[(size_t)(c0 + ty + i * 8) * ldD + r0 + tx] = f2bf(t[tx][ty + i * 8]);
}

// bf16 transpose with column offset: dst[c][r] = src[r][colOff+c]. block (32,8)
__global__ void transpose_bf16(const ushort_t* __restrict__ src, ushort_t* __restrict__ dst,
                               int ldS, int ldD, int colOff) {
  __shared__ ushort_t t[32][33];
  int r0 = blockIdx.x * 32, c0 = blockIdx.y * 32;
  int tx = threadIdx.x, ty = threadIdx.y;
#pragma unroll
  for (int i = 0; i < 4; ++i)
    t[ty + i * 8][tx] = src[(size_t)(r0 + ty + i * 8) * ldS + colOff + c0 + tx];
  __syncthreads();
#pragma unroll
  for (int i = 0; i < 4; ++i)
    dst[(size_t)(c0 + ty + i * 8) * ldD + r0 + tx] = t[tx][ty + i * 8];
}

// ---------------------------------------------------------------- 8-phase GEMM
// C[M][N] = A[M][K] (bf16 rm) x Bt[N][K]^T (bf16 rm) + epilogue.
// Tile BM x 256, BK=64, 512 threads (8 waves), double-buffered LDS.
// Quadrant-cooperative schedule: all 8 waves compute one 128-col C-quadrant per
// phase (Q00,Q01,Q11,Q10); A-frags persist 2 phases, B-frags persist across the
// quadrant pair that shares the B-half. Staging: one half-tile per phase
// (order A0,B0,B1,A1) targeting the *other* buffer, counted vmcnt (never 0 in
// steady state). LDS rows (128 B) are XOR-swizzled: slot ^= row&7, applied to
// the global source address (linear global_load_lds dest) and to ds_read.
template <int MODE, int BM>
__global__ __launch_bounds__(512, 2)
void gemm8p(const ushort_t* __restrict__ A, const ushort_t* __restrict__ Bt,
            const float* __restrict__ bias, const float* __restrict__ resid,
            ushort_t* __restrict__ outb, float* __restrict__ outf,
            int M, int N, int K, int gridN) {
  constexpr int MF = BM / 64;   // M-frags per wave per quadrant
  constexpr int LA = BM / 128;  // A chunks per thread per half-stage
  constexpr int AT = BM * 64;   // A tile elements
  constexpr int BT = 256 * 64;  // B tile elements
  __shared__ __align__(16) ushort_t Abuf[2][AT];
  __shared__ __align__(16) ushort_t Bbuf[2][BT];

  const int tid = threadIdx.x;
  const int l = tid & 63, w = tid >> 6;
  const int c16 = l & 15, g = l >> 4;
  const int wr2 = w >> 2, wc4 = w & 3;

  // bijective XCD swizzle (m204); consecutive wgid share the A row-panel
  const int nwg = gridDim.x;
  const int q8 = nwg >> 3, r8 = nwg & 7;
  const int xcd = blockIdx.x & 7, bix = blockIdx.x >> 3;
  const int wgid = (xcd < r8 ? xcd * (q8 + 1) : r8 * (q8 + 1) + (xcd - r8) * q8) + bix;
  const int m0 = (wgid / gridN) * BM;
  const int n0 = (wgid % gridN) * 256;

  const size_t Kb = (size_t)K * 2;

  // staging invariants: chunk ch covers LDS bytes [ch*16, ch*16+16); its
  // content is the element at slot (ch&7)^(row&7) of row ch>>3 (pre-swizzled
  // global source, linear LDS dest).
  const char* aSrc[LA]; char* aLds[LA];
#pragma unroll
  for (int i = 0; i < LA; ++i) {
    int ch = i * 512 + tid;
    int row = ch >> 3;
    int slot = ((ch ^ row) & 7) << 4;
    aSrc[i] = (const char*)A + (size_t)(m0 + row) * Kb + slot;
    aLds[i] = (char*)(&Abuf[0][0]) + ch * 16;
  }
  const char* bSrc[2]; char* bLds[2];
#pragma unroll
  for (int i = 0; i < 2; ++i) {
    int ch = i * 512 + tid;
    int row = ch >> 3;
    int slot = ((ch ^ row) & 7) << 4;
    bSrc[i] = (const char*)Bt + (size_t)(n0 + row) * Kb + slot;
    bLds[i] = (char*)(&Bbuf[0][0]) + ch * 16;
  }
  const size_t aHalf = (size_t)(BM / 2) * Kb;
  const size_t bHalf = (size_t)128 * Kb;

  // ds_read lane offsets: logical slot kk*4+g, swizzled by row&7 == c16&7
  int rdK[2];
  rdK[0] = ((g ^ (c16 & 7)) << 4);
  rdK[1] = (((4 + g) ^ (c16 & 7)) << 4);
  const int aRd = wr2 * (BM / 4) * 128 + c16 * 128;
  const int bRd = wc4 * 32 * 128 + c16 * 128;

  floatx4 acc[2][2][MF][2];
#pragma unroll
  for (int mh = 0; mh < 2; ++mh)
#pragma unroll
    for (int nh = 0; nh < 2; ++nh)
#pragma unroll
      for (int mf = 0; mf < MF; ++mf)
#pragma unroll
        for (int nf = 0; nf < 2; ++nf) acc[mh][nh][mf][nf] = (floatx4){0.f, 0.f, 0.f, 0.f};

  const int NT = K >> 6;

  // ---- prologue: stage K-tile 0 in order A0, B0, B1, A1
#pragma unroll
  for (int i = 0; i < LA; ++i) async16(aLds[i], aSrc[i]);
#pragma unroll
  for (int i = 0; i < 2; ++i) async16(bLds[i], bSrc[i]);
#pragma unroll
  for (int i = 0; i < 2; ++i) async16(bLds[i] + 128 * 128, bSrc[i] + bHalf);
#pragma unroll
  for (int i = 0; i < LA; ++i) async16(aLds[i] + (BM / 2) * 128, aSrc[i] + aHalf);
  vmcnt_<2 + LA>();  // A0,B0 of tile 0 resident
  bar_();

  for (int T = 0; T < NT; ++T) {
    const int kb = T & 1, kn = kb ^ 1;
    const bool last = (T == NT - 1);
    const size_t kOff = (size_t)(T + 1) << 7;  // next K-tile byte offset in global
    const char* ab = (const char*)(&Abuf[0][0]) + kb * (AT * 2);
    const char* bb = (const char*)(&Bbuf[0][0]) + kb * (BT * 2);
    const int aOf = kn * (AT * 2), bOf = kn * (BT * 2);
    short8 af[MF][2], bf0[2][2], bf1[2][2];

    // ---------- phase 0: read A(h0), B(h0); stage A-h0(T+1); MFMA Q00
#pragma unroll
    for (int mf = 0; mf < MF; ++mf)
#pragma unroll
      for (int kk = 0; kk < 2; ++kk)
        af[mf][kk] = *(const short8*)(ab + aRd + mf * 2048 + rdK[kk]);
#pragma unroll
    for (int nf = 0; nf < 2; ++nf)
#pragma unroll
      for (int kk = 0; kk < 2; ++kk)
        bf0[nf][kk] = *(const short8*)(bb + bRd + nf * 2048 + rdK[kk]);
    if (!last) {
#pragma unroll
      for (int i = 0; i < LA; ++i) async16(aLds[i] + aOf, aSrc[i] + kOff);
    }
    bar_();
    __builtin_amdgcn_s_setprio(1);
#pragma unroll
    for (int mf = 0; mf < MF; ++mf)
#pragma unroll
      for (int nf = 0; nf < 2; ++nf)
#pragma unroll
        for (int kk = 0; kk < 2; ++kk)
          acc[0][0][mf][nf] = __builtin_amdgcn_mfma_f32_16x16x32_bf16(
              af[mf][kk], bf0[nf][kk], acc[0][0][mf][nf], 0, 0, 0);
    __builtin_amdgcn_s_setprio(0);
    __builtin_amdgcn_sched_barrier(0);
    if (!last) vmcnt_<2 * LA>(); else vmcnt_<LA>();  // B1(T) resident
    bar_();

    // ---------- phase 1: read B(h1); stage B-h0(T+1); MFMA Q01
#pragma unroll
    for (int nf = 0; nf < 2; ++nf)
#pragma unroll
      for (int kk = 0; kk < 2; ++kk)
        bf1[nf][kk] = *(const short8*)(bb + bRd + 16384 + nf * 2048 + rdK[kk]);
    if (!last) {
#pragma unroll
      for (int i = 0; i < 2; ++i) async16(bLds[i] + bOf, bSrc[i] + kOff);
    }
    bar_();
    __builtin_amdgcn_s_setprio(1);
#pragma unroll
    for (int mf = 0; mf < MF; ++mf)
#pragma unroll
      for (int nf = 0; nf < 2; ++nf)
#pragma unroll
        for (int kk = 0; kk < 2; ++kk)
          acc[0][1][mf][nf] = __builtin_amdgcn_mfma_f32_16x16x32_bf16(
              af[mf][kk], bf1[nf][kk], acc[0][1][mf][nf], 0, 0, 0);
    __builtin_amdgcn_s_setprio(0);
    __builtin_amdgcn_sched_barrier(0);
    if (!last) vmcnt_<LA + 2>(); else vmcnt_<0>();  // A1(T) resident
    bar_();

    // ---------- phase 2: read A(h1); stage B-h1(T+1); MFMA Q11
#pragma unroll
    for (int mf = 0; mf < MF; ++mf)
#pragma unroll
      for (int kk = 0; kk < 2; ++kk)
        af[mf][kk] = *(const short8*)(ab + aRd + (BM / 2) * 128 + mf * 2048 + rdK[kk]);
    if (!last) {
#pragma unroll
      for (int i = 0; i < 2; ++i) async16(bLds[i] + bOf + 16384, bSrc[i] + bHalf + kOff);
    }
    bar_();
    __builtin_amdgcn_s_setprio(1);
#pragma unroll
    for (int mf = 0; mf < MF; ++mf)
#pragma unroll
      for (int nf = 0; nf < 2; ++nf)
#pragma unroll
        for (int kk = 0; kk < 2; ++kk)
          acc[1][1][mf][nf] = __builtin_amdgcn_mfma_f32_16x16x32_bf16(
              af[mf][kk], bf1[nf][kk], acc[1][1][mf][nf], 0, 0, 0);
    __builtin_amdgcn_s_setprio(0);
    __builtin_amdgcn_sched_barrier(0);
    bar_();

    // ---------- phase 3: stage A-h1(T+1); MFMA Q10 (regs only)
    if (!last) {
#pragma unroll
      for (int i = 0; i < LA; ++i) async16(aLds[i] + aOf + (BM / 2) * 128, aSrc[i] + aHalf + kOff);
    }
    bar_();
    __builtin_amdgcn_s_setprio(1);
#pragma unroll
    for (int mf = 0; mf < MF; ++mf)
#pragma unroll
      for (int nf = 0; nf < 2; ++nf)
#pragma unroll
        for (int kk = 0; kk < 2; ++kk)
          acc[1][0][mf][nf] = __builtin_amdgcn_mfma_f32_16x16x32_bf16(
              af[mf][kk], bf0[nf][kk], acc[1][0][mf][nf], 0, 0, 0);
    __builtin_amdgcn_s_setprio(0);
    __builtin_amdgcn_sched_barrier(0);
    if (!last) vmcnt_<2 + LA>();  // A0,B0(T+1) resident for next q0
    bar_();
  }

  // ---- epilogue
  const int mBase = m0 + wr2 * (BM / 4) + g * 4;
  const int nBase = n0 + wc4 * 32 + c16;
#pragma unroll
  for (int mh = 0; mh < 2; ++mh)
#pragma unroll
    for (int nh = 0; nh < 2; ++nh)
#pragma unroll
      for (int nf = 0; nf < 2; ++nf) {
        int gcol = nBase + nh * 128 + nf * 16;
        float bj = bias[gcol];
#pragma unroll
        for (int mf = 0; mf < MF; ++mf) {
          int grow = mBase + mh * (BM / 2) + mf * 16;
#pragma unroll
          for (int r = 0; r < 4; ++r) {
            float v = acc[mh][nh][mf][nf][r] + bj;
            size_t o = (size_t)(grow + r) * N + gcol;
            if (MODE == 0) {
              outb[o] = f2bf(v);
            } else if (MODE == 1) {
              outf[o] = v + resid[o];
            } else if (MODE == 2) {
              outb[o] = f2bf(v > 0.f ? v : 0.f);
            } else {
              outf[o] = v;
            }
          }
        }
      }
}

// ---------------------------------------------------------------- flash attention (v3)
__global__ __launch_bounds__(256, 2)
void attn_kernel(const ushort_t* __restrict__ QKV, const ushort_t* __restrict__ Vt,
                 ushort_t* __restrict__ heads) {
  const int h = blockIdx.y;
  const int tid = threadIdx.x, w = tid >> 6, l = tid & 63;
  const int g = l >> 4, c = l & 15;
  const int q0 = blockIdx.x * 128 + w * 32;
  const float scale = 0.08838834764831845f;  // 1/sqrt(128)

  __shared__ __align__(16) ushort_t Ks[64 * 128];   // [t][d] rows 256B, chunk-swizzled
  __shared__ __align__(16) ushort_t Vs[128 * 64];   // [e][t] rows 128B, chunk-swizzled
  __shared__ __align__(16) ushort_t Ps[4][2][16][72];  // wave-private P, pad-72

  short8 qf[2][4];
#pragma unroll
  for (int u = 0; u < 2; ++u)
#pragma unroll
    for (int k0 = 0; k0 < 4; ++k0)
      qf[u][k0] = *(const short8*)(QKV + (size_t)(q0 + u * 16 + c) * (3 * D) + h * HD + k0 * 32 + g * 8);

  floatx4 o[2][8];
#pragma unroll
  for (int u = 0; u < 2; ++u)
#pragma unroll
    for (int j = 0; j < 8; ++j) o[u][j] = (floatx4){0.f, 0.f, 0.f, 0.f};
  float l_run[2] = {0.f, 0.f};

  for (int t0 = 0; t0 < S; t0 += 64) {
#pragma unroll
    for (int cc = 0; cc < 4; ++cc) {
      int slot = cc * 256 + tid;
      int krow = slot >> 4, kch = slot & 15;
      const char* gk = (const char*)QKV +
          ((size_t)(t0 + krow) * (3 * D) + D + h * HD) * 2 + ((kch ^ (krow & 15)) << 4);
      async16((char*)Ks + (size_t)(cc * 256 + w * 64) * 16, gk);
      int vrow = slot >> 3, vch = slot & 7;
      const char* gv = (const char*)Vt +
          ((size_t)(h * HD + vrow) * S + t0) * 2 + ((vch ^ (vrow & 7)) << 4);
      async16((char*)Vs + (size_t)(cc * 256 + w * 64) * 16, gv);
    }
    __syncthreads();

    floatx4 sc[2][4];
#pragma unroll
    for (int u = 0; u < 2; ++u)
#pragma unroll
      for (int tt = 0; tt < 4; ++tt) sc[u][tt] = (floatx4){0.f, 0.f, 0.f, 0.f};
#pragma unroll
    for (int tt = 0; tt < 4; ++tt) {
      short8 kf[4];
#pragma unroll
      for (int k0 = 0; k0 < 4; ++k0)
        kf[k0] = *(const short8*)(Ks + (tt * 16 + c) * 128 + (((k0 * 4 + g) ^ c) << 3));
#pragma unroll
      for (int u = 0; u < 2; ++u)
#pragma unroll
        for (int k0 = 0; k0 < 4; ++k0)
          sc[u][tt] = __builtin_amdgcn_mfma_f32_16x16x32_bf16(kf[k0], qf[u][k0], sc[u][tt], 0, 0, 0);
    }

#pragma unroll
    for (int u = 0; u < 2; ++u) {
#pragma unroll
      for (int tt = 0; tt < 4; ++tt) {
        float p0 = __expf(sc[u][tt][0] * scale);
        float p1 = __expf(sc[u][tt][1] * scale);
        float p2 = __expf(sc[u][tt][2] * scale);
        float p3 = __expf(sc[u][tt][3] * scale);
        l_run[u] += p0 + p1 + p2 + p3;
        ushort4 pk;
        pk.x = f2bf(p0); pk.y = f2bf(p1); pk.z = f2bf(p2); pk.w = f2bf(p3);
        *reinterpret_cast<ushort4*>(&Ps[w][u][c][tt * 16 + g * 4]) = pk;
      }
    }
    __asm__ volatile("s_waitcnt lgkmcnt(0)" ::: "memory");

    short8 pf[2][2];
#pragma unroll
    for (int u = 0; u < 2; ++u)
#pragma unroll
      for (int tk = 0; tk < 2; ++tk)
        pf[u][tk] = *reinterpret_cast<const short8*>(&Ps[w][u][c][tk * 32 + g * 8]);
#pragma unroll
    for (int j = 0; j < 8; ++j) {
#pragma unroll
      for (int tk = 0; tk < 2; ++tk) {
        short8 vf = *(const short8*)(Vs + (j * 16 + c) * 64 + (((tk * 4 + g) ^ (c & 7)) << 3));
#pragma unroll
        for (int u = 0; u < 2; ++u)
          o[u][j] = __builtin_amdgcn_mfma_f32_16x16x32_bf16(pf[u][tk], vf, o[u][j], 0, 0, 0);
      }
    }
    __syncthreads();
  }

#pragma unroll
  for (int u = 0; u < 2; ++u) {
    float lt = l_run[u];
    lt += __shfl_xor(lt, 16);
    lt += __shfl_xor(lt, 32);
    float linv[4];
#pragma unroll
    for (int r = 0; r < 4; ++r) linv[r] = 1.f / __shfl(lt, g * 4 + r);
    ushort_t* hp = heads + (size_t)(q0 + u * 16 + g * 4) * D + h * HD + c;
#pragma unroll
    for (int j = 0; j < 8; ++j)
#pragma unroll
      for (int r = 0; r < 4; ++r)
        hp[(size_t)r * D + j * 16] = f2bf(o[u][j][r] * linv[r]);
  }
}

// ---------------------------------------------------------------- LayerNorm
__global__ __launch_bounds__(256)
void ln_kernel(const float* __restrict__ preln, const float* __restrict__ gamma,
               const float* __restrict__ beta, ushort_t* __restrict__ y) {
  int row = blockIdx.x, tid = threadIdx.x;
  const float* p = preln + (size_t)row * D;
  float vals[8];
  float sum = 0.f, ss = 0.f;
#pragma unroll
  for (int k = 0; k < 8; ++k) {
    float v = p[tid + k * 256];
    vals[k] = v; sum += v; ss += v * v;
  }
#pragma unroll
  for (int off = 32; off >= 1; off >>= 1) {
    sum += __shfl_xor(sum, off);
    ss += __shfl_xor(ss, off);
  }
  __shared__ float s1[4], s2[4];
  int w = tid >> 6, l = tid & 63;
  if (l == 0) { s1[w] = sum; s2[w] = ss; }
  __syncthreads();
  sum = s1[0] + s1[1] + s1[2] + s1[3];
  ss = s2[0] + s2[1] + s2[2] + s2[3];
  float mu = sum / (float)D;
  float var = ss / (float)D - mu * mu;
  float rs = rsqrtf(var + 1e-5f);
  ushort_t* yr = y + (size_t)row * D;
#pragma unroll
  for (int k = 0; k < 8; ++k) {
    int d = tid + k * 256;
    yr[d] = f2bf((vals[k] - mu) * rs * gamma[d] + beta[d]);
  }
}

// ---------------------------------------------------------------- launch

extern "C" void kernel_launch(void* const* d_in, const int* in_sizes, int n_in,
                              void* d_out, int out_size, void* d_ws, size_t ws_size,
                              hipStream_t stream) {
  const float* x = (const float*)d_in[0];
  const float* Wq = (const float*)d_in[1];
  const float* bq = (const float*)d_in[2];
  const float* Wk = (const float*)d_in[3];
  const float* bk = (const float*)d_in[4];
  const float* Wv = (const float*)d_in[5];
  const float* bv = (const float*)d_in[6];
  const float* Wp = (const float*)d_in[7];
  const float* bp = (const float*)d_in[8];
  const float* W1 = (const float*)d_in[9];
  const float* b1 = (const float*)d_in[10];
  const float* W2 = (const float*)d_in[11];
  const float* b2 = (const float*)d_in[12];
  const float* gamma = (const float*)d_in[13];
  const float* beta = (const float*)d_in[14];

  char* ws = (char*)d_ws;
  ushort_t* WQKVT = (ushort_t*)(ws + 0);          // 25,165,824  [dead after QKV gemm]
  ushort_t* XB    = (ushort_t*)(ws + 25165824);   // 16,777,216  [dead after QKV gemm]
  float*    BQKV  = (float*)(ws + 41943040);      //     24,576
  ushort_t* WPT   = (ushort_t*)(ws + 41975808);   //  8,388,608
  ushort_t* W1T   = (ushort_t*)(ws + 50364416);   // 33,554,432
  ushort_t* W2T   = (ushort_t*)(ws + 83918848);   // 33,554,432
  ushort_t* QKV   = (ushort_t*)(ws + 117473280);  // 50,331,648  [dead after attn]
  ushort_t* HEADS = (ushort_t*)(ws + 167804928);  // 16,777,216  [dead after proj]
  ushort_t* VT    = (ushort_t*)(ws + 184582144);  // 16,777,216  [dead after attn]
  float*    PRELN = (float*)(ws + 0);             // 33,554,432 over WQKVT+XB
  ushort_t* AB    = (ushort_t*)(ws + 117473280);  // 67,108,864 over QKV+HEADS
  ushort_t* Y     = (ushort_t*)(ws + 184582144);  // 16,777,216 over VT
  float* OUT = (float*)d_out;

  dim3 tb(32, 8);
  cast_bf16<<<(S * D / 4 + 255) / 256, 256, 0, stream>>>(x, XB, S * D / 4);
  build_bqkv<<<(3 * D + 255) / 256, 256, 0, stream>>>(bq, bk, bv, BQKV);
  transpose_f32_bf16<<<dim3(D / 32, HD / 32, H), tb, 0, stream>>>(Wq, WQKVT, HD, D, (long)D * HD, HD);
  transpose_f32_bf16<<<dim3(D / 32, HD / 32, H), tb, 0, stream>>>(Wk, WQKVT + (size_t)D * D, HD, D, (long)D * HD, HD);
  transpose_f32_bf16<<<dim3(D / 32, HD / 32, H), tb, 0, stream>>>(Wv, WQKVT + (size_t)2 * D * D, HD, D, (long)D * HD, HD);
  transpose_f32_bf16<<<dim3(D / 32, D / 32, 1), tb, 0, stream>>>(Wp, WPT, D, D, 0, 0);
  transpose_f32_bf16<<<dim3(D / 32, F / 32, 1), tb, 0, stream>>>(W1, W1T, F, D, 0, 0);
  transpose_f32_bf16<<<dim3(F / 32, D / 32, 1), tb, 0, stream>>>(W2, W2T, D, F, 0, 0);
  // QKV projection (fused, N=6144): 16x24 = 384 blocks
  gemm8p<0, 256><<<dim3((S / 256) * (3 * D / 256)), 512, 0, stream>>>(
      XB, WQKVT, BQKV, nullptr, QKV, nullptr, S, 3 * D, D, 3 * D / 256);
  transpose_bf16<<<dim3(S / 32, D / 32), tb, 0, stream>>>(QKV, VT, 3 * D, S, 2 * D);
  attn_kernel<<<dim3(S / 128, H), 256, 0, stream>>>(QKV, VT, HEADS);
  // output projection + bias + residual -> fp32 pre-LN: 32x8 = 256 blocks (BM=128)
  gemm8p<1, 128><<<dim3((S / 128) * (D / 256)), 512, 0, stream>>>(
      HEADS, WPT, bp, x, nullptr, PRELN, S, D, D, D / 256);
  ln_kernel<<<S, 256, 0, stream>>>(PRELN, gamma, beta, Y);
  // FF1 (+bias, relu) -> bf16: 16x32 = 512 blocks
  gemm8p<2, 256><<<dim3((S / 256) * (F / 256)), 512, 0, stream>>>(
      Y, W1T, b1, nullptr, AB, nullptr, S, F, D, F / 256);
  // FF2 (+bias) -> fp32 out: 32x8 = 256 blocks (BM=128)
  gemm8p<3, 128><<<dim3((S / 128) * (D / 256)), 512, 0, stream>>>(
      AB, W2T, b2, nullptr, nullptr, OUT, S, D, F, D / 256);
}

// Round 3
// 956.223 us; speedup vs baseline: 1.0882x; 1.0029x over previous
//
#include <hip/hip_runtime.h>
#include <hip/hip_bf16.h>
#include <cstdint>
#include <cstddef>

#define S 4096
#define D 2048
#define H 16
#define HD 128
#define F 8192

typedef unsigned short ushort_t;
typedef __attribute__((ext_vector_type(8))) short short8;
typedef __attribute__((ext_vector_type(4))) float floatx4;

__device__ __forceinline__ ushort_t f2bf(float f) {
  union { float f; unsigned u; } v; v.f = f;
  unsigned u = v.u;
  return (ushort_t)((u + 0x7fffu + ((u >> 16) & 1u)) >> 16);
}

__device__ __forceinline__ void async16(void* lds, const void* g) {
  __builtin_amdgcn_global_load_lds(
      (const __attribute__((address_space(1))) unsigned int*)g,
      (__attribute__((address_space(3))) unsigned int*)lds, 16, 0, 0);
}

template <int N>
__device__ __forceinline__ void vmcnt_() {
  static_assert(N >= 0 && N <= 8, "vmcnt range");
  if constexpr (N == 0) asm volatile("s_waitcnt vmcnt(0)" ::: "memory");
  else if constexpr (N == 1) asm volatile("s_waitcnt vmcnt(1)" ::: "memory");
  else if constexpr (N == 2) asm volatile("s_waitcnt vmcnt(2)" ::: "memory");
  else if constexpr (N == 3) asm volatile("s_waitcnt vmcnt(3)" ::: "memory");
  else if constexpr (N == 4) asm volatile("s_waitcnt vmcnt(4)" ::: "memory");
  else if constexpr (N == 5) asm volatile("s_waitcnt vmcnt(5)" ::: "memory");
  else if constexpr (N == 6) asm volatile("s_waitcnt vmcnt(6)" ::: "memory");
  else if constexpr (N == 7) asm volatile("s_waitcnt vmcnt(7)" ::: "memory");
  else asm volatile("s_waitcnt vmcnt(8)" ::: "memory");
}
__device__ __forceinline__ void bar_() { asm volatile("s_barrier" ::: "memory"); }
__device__ __forceinline__ void lgkm0_() {
  asm volatile("s_waitcnt lgkmcnt(0)" ::: "memory");
  __builtin_amdgcn_sched_barrier(0);
}

// ---------------------------------------------------------------- prep kernels

__global__ void cast_bf16(const float* __restrict__ src, ushort_t* __restrict__ dst, int n4) {
  int i = blockIdx.x * blockDim.x + threadIdx.x;
  if (i < n4) {
    float4 v = ((const float4*)src)[i];
    ushort4 o;
    o.x = f2bf(v.x); o.y = f2bf(v.y); o.z = f2bf(v.z); o.w = f2bf(v.w);
    ((ushort4*)dst)[i] = o;
  }
}

__global__ void build_bqkv(const float* __restrict__ bq, const float* __restrict__ bk,
                           const float* __restrict__ bv, float* __restrict__ bqkv) {
  int n = blockIdx.x * blockDim.x + threadIdx.x;
  if (n < 3 * D) {
    float v;
    if (n < D) v = bq[n];
    else if (n < 2 * D) v = bk[n - D];
    else v = bv[n - 2 * D];
    bqkv[n] = v;
  }
}

// dst[c][r] = src[r][c]; fp32 in, bf16 out. block (32,8)
__global__ void transpose_f32_bf16(const float* __restrict__ src, ushort_t* __restrict__ dst,
                                   int ldS, int ldD, long srcBatchStride, long dstBatchRows) {
  __shared__ float t[32][33];
  int b = blockIdx.z;
  src += (size_t)b * srcBatchStride;
  dst += (size_t)b * dstBatchRows * ldD;
  int r0 = blockIdx.x * 32, c0 = blockIdx.y * 32;
  int tx = threadIdx.x, ty = threadIdx.y;
#pragma unroll
  for (int i = 0; i < 4; ++i)
    t[ty + i * 8][tx] = src[(size_t)(r0 + ty + i * 8) * ldS + c0 + tx];
  __syncthreads();
#pragma unroll
  for (int i = 0; i < 4; ++i)
    dst[(size_t)(c0 + ty + i * 8) * ldD + r0 + tx] = f2bf(t[tx][ty + i * 8]);
}

// bf16 transpose with column offset: dst[c][r] = src[r][colOff+c]. block (32,8)
__global__ void transpose_bf16(const ushort_t* __restrict__ src, ushort_t* __restrict__ dst,
                               int ldS, int ldD, int colOff) {
  __shared__ ushort_t t[32][33];
  int r0 = blockIdx.x * 32, c0 = blockIdx.y * 32;
  int tx = threadIdx.x, ty = threadIdx.y;
#pragma unroll
  for (int i = 0; i < 4; ++i)
    t[ty + i * 8][tx] = src[(size_t)(r0 + ty + i * 8) * ldS + colOff + c0 + tx];
  __syncthreads();
#pragma unroll
  for (int i = 0; i < 4; ++i)
    dst[(size_t)(c0 + ty + i * 8) * ldD + r0 + tx] = t[tx][ty + i * 8];
}

// ---------------------------------------------------------------- 8-phase GEMM (m201 schedule)
// C[M][N] = A[M][K] (bf16 rm) x Bt[N][K]^T (bf16 rm) + epilogue.
// Tile BM x 256, BK=64, 512 threads (8 waves), LDS double-buffer
// (even K-tile -> buf0, odd -> buf1; all buffer indices compile-time).
// 8 phases per 2 K-tiles. Per phase: {ds_read HALF-ALIGNED frag subtile;
// stage ONE half-tile of a future K-tile; barrier; lgkmcnt(0); setprio(1);
// MFMA quadrant; setprio(0); [vmcnt(LA+4) at phases 4 & 8 only]; barrier}.
// HALF-ALIGNED is load-bearing: ldA(h) reads ONLY rows of staged half h
// (h*(BM/2) + wm*(BM/4) + mf*16 + c16), ldB(h) only h*128 + wn*32 + nf*16
// + c16 -- so the overwrite ledger holds: each staged half is rewritten
// >=1 barrier after its last ds_read (A0: ph1->ph2; B0: ph1->ph3;
// B1: ph2->ph4; A1: ph3->ph5; mirrored for the odd tile). Round-2's
// misaligned mapping (wm*(BM/2)+mq*(BM/4)) broke exactly this.
// Prologue stages 7 half-tiles (T0 full + T1 {A0,B0,B1}); steady state keeps
// 3 half-tiles (LA+4 loads) in flight -> each load has ~5-7 phases of slack.
// LDS rows (128B) XOR-swizzled both-sides: slot ^= row&7 on the pre-swizzled
// global source (linear global_load_lds dest) and on ds_read.
template <int MODE, int BM>
__global__ __launch_bounds__(512, 2)
void gemm8p(const ushort_t* __restrict__ A, const ushort_t* __restrict__ Bt,
            const float* __restrict__ bias, const float* __restrict__ resid,
            ushort_t* __restrict__ outb, float* __restrict__ outf,
            int M, int N, int K, int gridN) {
  constexpr int MQ = BM / 64;   // m-frags per wave per A-half
  constexpr int LA = BM / 128;  // loads/thread per A half-tile
  __shared__ __align__(16) ushort_t Abuf[2][BM * 64];
  __shared__ __align__(16) ushort_t Bbuf[2][256 * 64];

  const int tid = threadIdx.x;
  const int l = tid & 63, w = tid >> 6;
  const int c16 = l & 15, g = l >> 4;
  const int wm = w >> 2, wn = w & 3;

  // bijective XCD swizzle (m204); consecutive wgid share the A row-panel
  const int nwg = gridDim.x;
  const int q8 = nwg >> 3, r8 = nwg & 7;
  const int xcd = blockIdx.x & 7, bix = blockIdx.x >> 3;
  const int wgid = (xcd < r8 ? xcd * (q8 + 1) : r8 * (q8 + 1) + (xcd - r8) * q8) + bix;
  const int m0 = (wgid / gridN) * BM;
  const int n0 = (wgid % gridN) * 256;

  const size_t Kb = (size_t)K * 2;
  const size_t aHalfB = (size_t)(BM / 2) * Kb;
  const size_t bHalfB = (size_t)128 * Kb;

  // staging: chunk ch -> LDS bytes [ch*16, +16); content = global slot
  // (ch&7)^(row&7) of row ch>>3 (pre-swizzled source, linear dest).
  const char* aSrc[LA]; char* aLds[LA];
#pragma unroll
  for (int i = 0; i < LA; ++i) {
    int ch = i * 512 + tid;
    int row = ch >> 3;
    aSrc[i] = (const char*)A + (size_t)(m0 + row) * Kb + (((ch ^ row) & 7) << 4);
    aLds[i] = (char*)(&Abuf[0][0]) + ch * 16;
  }
  const char* bSrc[2]; char* bLds[2];
#pragma unroll
  for (int i = 0; i < 2; ++i) {
    int ch = i * 512 + tid;
    int row = ch >> 3;
    bSrc[i] = (const char*)Bt + (size_t)(n0 + row) * Kb + (((ch ^ row) & 7) << 4);
    bLds[i] = (char*)(&Bbuf[0][0]) + ch * 16;
  }

  auto stA = [&](int p, int h, int kByte) {
#pragma unroll
    for (int i = 0; i < LA; ++i)
      async16(aLds[i] + p * (BM * 128) + h * (BM * 64), aSrc[i] + (size_t)h * aHalfB + kByte);
  };
  auto stB = [&](int p, int h, int kByte) {
#pragma unroll
    for (int i = 0; i < 2; ++i)
      async16(bLds[i] + p * 32768 + h * 16384, bSrc[i] + (size_t)h * bHalfB + kByte);
  };

  // ds_read lane offsets: logical slot kk*4+g, swizzled by row&7 == c16&7
  int rdK[2];
  rdK[0] = ((g ^ (c16 & 7)) << 4);
  rdK[1] = (((4 + g) ^ (c16 & 7)) << 4);
  const char* Ab0 = (const char*)(&Abuf[0][0]);
  const char* Ab1 = Ab0 + BM * 128;
  const char* Bb0 = (const char*)(&Bbuf[0][0]);
  const char* Bb1 = Bb0 + 32768;

  floatx4 acc[2][2][MQ][2];  // [A-half][B-half][mf][nf]
#pragma unroll
  for (int ah = 0; ah < 2; ++ah)
#pragma unroll
    for (int bh = 0; bh < 2; ++bh)
#pragma unroll
      for (int mf = 0; mf < MQ; ++mf)
#pragma unroll
        for (int nf = 0; nf < 2; ++nf) acc[ah][bh][mf][nf] = (floatx4){0.f, 0.f, 0.f, 0.f};

  short8 af[MQ][2], bf0[2][2], bf1[2][2];
  // HALF-ALIGNED reads (see header comment).
  auto ldA = [&](const char* base, int h) {
#pragma unroll
    for (int mf = 0; mf < MQ; ++mf)
#pragma unroll
      for (int kk = 0; kk < 2; ++kk)
        af[mf][kk] = *(const short8*)(base + h * (BM * 64) +
            (wm * (BM / 4) + mf * 16 + c16) * 128 + rdK[kk]);
  };
  auto ldB = [&](const char* base, int h, short8 (&bf)[2][2]) {
#pragma unroll
    for (int nf = 0; nf < 2; ++nf)
#pragma unroll
      for (int kk = 0; kk < 2; ++kk)
        bf[nf][kk] = *(const short8*)(base + h * 16384 +
            (wn * 32 + nf * 16 + c16) * 128 + rdK[kk]);
  };
  auto mmaQ = [&](int ah, int bh, short8 (&bf)[2][2]) {
    __builtin_amdgcn_s_setprio(1);
#pragma unroll
    for (int mf = 0; mf < MQ; ++mf)
#pragma unroll
      for (int nf = 0; nf < 2; ++nf)
#pragma unroll
        for (int kk = 0; kk < 2; ++kk)
          acc[ah][bh][mf][nf] = __builtin_amdgcn_mfma_f32_16x16x32_bf16(
              af[mf][kk], bf[nf][kk], acc[ah][bh][mf][nf], 0, 0, 0);
    __builtin_amdgcn_s_setprio(0);
  };

  // ---- prologue: T0 {A0,B0,B1,A1} + T1 {A0,B0,B1}; leave T1's 3 halves in flight
  stA(0, 0, 0); stB(0, 0, 0); stB(0, 1, 0); stA(0, 1, 0);
  stA(1, 0, 128); stB(1, 0, 128); stB(1, 1, 128);
  vmcnt_<LA + 4>();
  bar_();

  const int NI = K >> 7;  // iterations of 2 K-tiles
  for (int i = 0; i < NI; ++i) {
    const bool lastI = (i == NI - 1);
    const int kE = i << 8;  // even-tile K byte offset (tile 2i)

    // ph1: read A0,B0 (buf0); stage T1.A1; MFMA acc[0][0]
    ldA(Ab0, 0); ldB(Bb0, 0, bf0);
    stA(1, 1, kE + 128);
    bar_(); lgkm0_();
    mmaQ(0, 0, bf0);
    __builtin_amdgcn_sched_barrier(0);
    bar_();

    // ph2: read B1 (buf0); stage T2.A0; MFMA acc[0][1]
    ldB(Bb0, 1, bf1);
    if (!lastI) stA(0, 0, kE + 256);
    bar_(); lgkm0_();
    mmaQ(0, 1, bf1);
    __builtin_amdgcn_sched_barrier(0);
    bar_();

    // ph3: read A1 (buf0); stage T2.B0; MFMA acc[1][1]
    ldA(Ab0, 1);
    if (!lastI) stB(0, 0, kE + 256);
    bar_(); lgkm0_();
    mmaQ(1, 1, bf1);
    __builtin_amdgcn_sched_barrier(0);
    bar_();

    // ph4: stage T2.B1; MFMA acc[1][0]; vmcnt -> all of T1 resident
    if (!lastI) stB(0, 1, kE + 256);
    bar_(); lgkm0_();
    mmaQ(1, 0, bf0);
    __builtin_amdgcn_sched_barrier(0);
    if (lastI) vmcnt_<0>(); else vmcnt_<LA + 4>();
    bar_();

    // ph5: read A0,B0 (buf1); stage T2.A1; MFMA acc[0][0]
    ldA(Ab1, 0); ldB(Bb1, 0, bf0);
    if (!lastI) stA(0, 1, kE + 256);
    bar_(); lgkm0_();
    mmaQ(0, 0, bf0);
    __builtin_amdgcn_sched_barrier(0);
    bar_();

    // ph6: read B1 (buf1); stage T3.A0; MFMA acc[0][1]
    ldB(Bb1, 1, bf1);
    if (!lastI) stA(1, 0, kE + 384);
    bar_(); lgkm0_();
    mmaQ(0, 1, bf1);
    __builtin_amdgcn_sched_barrier(0);
    bar_();

    // ph7: read A1 (buf1); stage T3.B0; MFMA acc[1][1]
    ldA(Ab1, 1);
    if (!lastI) stB(1, 0, kE + 384);
    bar_(); lgkm0_();
    mmaQ(1, 1, bf1);
    __builtin_amdgcn_sched_barrier(0);
    bar_();

    // ph8: stage T3.B1; MFMA acc[1][0]; vmcnt -> all of T2 resident
    if (!lastI) stB(1, 1, kE + 384);
    bar_(); lgkm0_();
    mmaQ(1, 0, bf0);
    __builtin_amdgcn_sched_barrier(0);
    if (!lastI) { vmcnt_<LA + 4>(); bar_(); }
  }

  // ---- epilogue
#pragma unroll
  for (int ah = 0; ah < 2; ++ah)
#pragma unroll
    for (int bh = 0; bh < 2; ++bh)
#pragma unroll
      for (int nf = 0; nf < 2; ++nf) {
        int gcol = n0 + bh * 128 + wn * 32 + nf * 16 + c16;
        float bj = bias[gcol];
#pragma unroll
        for (int mf = 0; mf < MQ; ++mf) {
          int grow = m0 + ah * (BM / 2) + wm * (BM / 4) + mf * 16 + g * 4;
#pragma unroll
          for (int r = 0; r < 4; ++r) {
            float v = acc[ah][bh][mf][nf][r] + bj;
            size_t o = (size_t)(grow + r) * N + gcol;
            if (MODE == 0) {
              outb[o] = f2bf(v);
            } else if (MODE == 1) {
              outf[o] = v + resid[o];
            } else if (MODE == 2) {
              outb[o] = f2bf(v > 0.f ? v : 0.f);
            } else {
              outf[o] = v;
            }
          }
        }
      }
}

// ---------------------------------------------------------------- flash attention (v3)
__global__ __launch_bounds__(256, 2)
void attn_kernel(const ushort_t* __restrict__ QKV, const ushort_t* __restrict__ Vt,
                 ushort_t* __restrict__ heads) {
  const int h = blockIdx.y;
  const int tid = threadIdx.x, w = tid >> 6, l = tid & 63;
  const int g = l >> 4, c = l & 15;
  const int q0 = blockIdx.x * 128 + w * 32;
  const float scale = 0.08838834764831845f;  // 1/sqrt(128)

  __shared__ __align__(16) ushort_t Ks[64 * 128];   // [t][d] rows 256B, chunk-swizzled
  __shared__ __align__(16) ushort_t Vs[128 * 64];   // [e][t] rows 128B, chunk-swizzled
  __shared__ __align__(16) ushort_t Ps[4][2][16][72];  // wave-private P, pad-72

  short8 qf[2][4];
#pragma unroll
  for (int u = 0; u < 2; ++u)
#pragma unroll
    for (int k0 = 0; k0 < 4; ++k0)
      qf[u][k0] = *(const short8*)(QKV + (size_t)(q0 + u * 16 + c) * (3 * D) + h * HD + k0 * 32 + g * 8);

  floatx4 o[2][8];
#pragma unroll
  for (int u = 0; u < 2; ++u)
#pragma unroll
    for (int j = 0; j < 8; ++j) o[u][j] = (floatx4){0.f, 0.f, 0.f, 0.f};
  float l_run[2] = {0.f, 0.f};

  for (int t0 = 0; t0 < S; t0 += 64) {
#pragma unroll
    for (int cc = 0; cc < 4; ++cc) {
      int slot = cc * 256 + tid;
      int krow = slot >> 4, kch = slot & 15;
      const char* gk = (const char*)QKV +
          ((size_t)(t0 + krow) * (3 * D) + D + h * HD) * 2 + ((kch ^ (krow & 15)) << 4);
      async16((char*)Ks + (size_t)(cc * 256 + w * 64) * 16, gk);
      int vrow = slot >> 3, vch = slot & 7;
      const char* gv = (const char*)Vt +
          ((size_t)(h * HD + vrow) * S + t0) * 2 + ((vch ^ (vrow & 7)) << 4);
      async16((char*)Vs + (size_t)(cc * 256 + w * 64) * 16, gv);
    }
    __syncthreads();

    floatx4 sc[2][4];
#pragma unroll
    for (int u = 0; u < 2; ++u)
#pragma unroll
      for (int tt = 0; tt < 4; ++tt) sc[u][tt] = (floatx4){0.f, 0.f, 0.f, 0.f};
#pragma unroll
    for (int tt = 0; tt < 4; ++tt) {
      short8 kf[4];
#pragma unroll
      for (int k0 = 0; k0 < 4; ++k0)
        kf[k0] = *(const short8*)(Ks + (tt * 16 + c) * 128 + (((k0 * 4 + g) ^ c) << 3));
#pragma unroll
      for (int u = 0; u < 2; ++u)
#pragma unroll
        for (int k0 = 0; k0 < 4; ++k0)
          sc[u][tt] = __builtin_amdgcn_mfma_f32_16x16x32_bf16(kf[k0], qf[u][k0], sc[u][tt], 0, 0, 0);
    }

#pragma unroll
    for (int u = 0; u < 2; ++u) {
#pragma unroll
      for (int tt = 0; tt < 4; ++tt) {
        float p0 = __expf(sc[u][tt][0] * scale);
        float p1 = __expf(sc[u][tt][1] * scale);
        float p2 = __expf(sc[u][tt][2] * scale);
        float p3 = __expf(sc[u][tt][3] * scale);
        l_run[u] += p0 + p1 + p2 + p3;
        ushort4 pk;
        pk.x = f2bf(p0); pk.y = f2bf(p1); pk.z = f2bf(p2); pk.w = f2bf(p3);
        *reinterpret_cast<ushort4*>(&Ps[w][u][c][tt * 16 + g * 4]) = pk;
      }
    }
    __asm__ volatile("s_waitcnt lgkmcnt(0)" ::: "memory");

    short8 pf[2][2];
#pragma unroll
    for (int u = 0; u < 2; ++u)
#pragma unroll
      for (int tk = 0; tk < 2; ++tk)
        pf[u][tk] = *reinterpret_cast<const short8*>(&Ps[w][u][c][tk * 32 + g * 8]);
#pragma unroll
    for (int j = 0; j < 8; ++j) {
#pragma unroll
      for (int tk = 0; tk < 2; ++tk) {
        short8 vf = *(const short8*)(Vs + (j * 16 + c) * 64 + (((tk * 4 + g) ^ (c & 7)) << 3));
#pragma unroll
        for (int u = 0; u < 2; ++u)
          o[u][j] = __builtin_amdgcn_mfma_f32_16x16x32_bf16(pf[u][tk], vf, o[u][j], 0, 0, 0);
      }
    }
    __syncthreads();
  }

#pragma unroll
  for (int u = 0; u < 2; ++u) {
    float lt = l_run[u];
    lt += __shfl_xor(lt, 16);
    lt += __shfl_xor(lt, 32);
    float linv[4];
#pragma unroll
    for (int r = 0; r < 4; ++r) linv[r] = 1.f / __shfl(lt, g * 4 + r);
    ushort_t* hp = heads + (size_t)(q0 + u * 16 + g * 4) * D + h * HD + c;
#pragma unroll
    for (int j = 0; j < 8; ++j)
#pragma unroll
      for (int r = 0; r < 4; ++r)
        hp[(size_t)r * D + j * 16] = f2bf(o[u][j][r] * linv[r]);
  }
}

// ---------------------------------------------------------------- LayerNorm
__global__ __launch_bounds__(256)
void ln_kernel(const float* __restrict__ preln, const float* __restrict__ gamma,
               const float* __restrict__ beta, ushort_t* __restrict__ y) {
  int row = blockIdx.x, tid = threadIdx.x;
  const float* p = preln + (size_t)row * D;
  float vals[8];
  float sum = 0.f, ss = 0.f;
#pragma unroll
  for (int k = 0; k < 8; ++k) {
    float v = p[tid + k * 256];
    vals[k] = v; sum += v; ss += v * v;
  }
#pragma unroll
  for (int off = 32; off >= 1; off >>= 1) {
    sum += __shfl_xor(sum, off);
    ss += __shfl_xor(ss, off);
  }
  __shared__ float s1[4], s2[4];
  int w = tid >> 6, l = tid & 63;
  if (l == 0) { s1[w] = sum; s2[w] = ss; }
  __syncthreads();
  sum = s1[0] + s1[1] + s1[2] + s1[3];
  ss = s2[0] + s2[1] + s2[2] + s2[3];
  float mu = sum / (float)D;
  float var = ss / (float)D - mu * mu;
  float rs = rsqrtf(var + 1e-5f);
  ushort_t* yr = y + (size_t)row * D;
#pragma unroll
  for (int k = 0; k < 8; ++k) {
    int d = tid + k * 256;
    yr[d] = f2bf((vals[k] - mu) * rs * gamma[d] + beta[d]);
  }
}

// ---------------------------------------------------------------- launch

extern "C" void kernel_launch(void* const* d_in, const int* in_sizes, int n_in,
                              void* d_out, int out_size, void* d_ws, size_t ws_size,
                              hipStream_t stream) {
  const float* x = (const float*)d_in[0];
  const float* Wq = (const float*)d_in[1];
  const float* bq = (const float*)d_in[2];
  const float* Wk = (const float*)d_in[3];
  const float* bk = (const float*)d_in[4];
  const float* Wv = (const float*)d_in[5];
  const float* bv = (const float*)d_in[6];
  const float* Wp = (const float*)d_in[7];
  const float* bp = (const float*)d_in[8];
  const float* W1 = (const float*)d_in[9];
  const float* b1 = (const float*)d_in[10];
  const float* W2 = (const float*)d_in[11];
  const float* b2 = (const float*)d_in[12];
  const float* gamma = (const float*)d_in[13];
  const float* beta = (const float*)d_in[14];

  char* ws = (char*)d_ws;
  ushort_t* WQKVT = (ushort_t*)(ws + 0);          // 25,165,824  [dead after QKV gemm]
  ushort_t* XB    = (ushort_t*)(ws + 25165824);   // 16,777,216  [dead after QKV gemm]
  float*    BQKV  = (float*)(ws + 41943040);      //     24,576
  ushort_t* WPT   = (ushort_t*)(ws + 41975808);   //  8,388,608
  ushort_t* W1T   = (ushort_t*)(ws + 50364416);   // 33,554,432
  ushort_t* W2T   = (ushort_t*)(ws + 83918848);   // 33,554,432
  ushort_t* QKV   = (ushort_t*)(ws + 117473280);  // 50,331,648  [dead after attn]
  ushort_t* HEADS = (ushort_t*)(ws + 167804928);  // 16,777,216  [dead after proj]
  ushort_t* VT    = (ushort_t*)(ws + 184582144);  // 16,777,216  [dead after attn]
  float*    PRELN = (float*)(ws + 0);             // 33,554,432 over WQKVT+XB
  ushort_t* AB    = (ushort_t*)(ws + 117473280);  // 67,108,864 over QKV+HEADS
  ushort_t* Y     = (ushort_t*)(ws + 184582144);  // 16,777,216 over VT
  float* OUT = (float*)d_out;

  dim3 tb(32, 8);
  cast_bf16<<<(S * D / 4 + 255) / 256, 256, 0, stream>>>(x, XB, S * D / 4);
  build_bqkv<<<(3 * D + 255) / 256, 256, 0, stream>>>(bq, bk, bv, BQKV);
  transpose_f32_bf16<<<dim3(D / 32, HD / 32, H), tb, 0, stream>>>(Wq, WQKVT, HD, D, (long)D * HD, HD);
  transpose_f32_bf16<<<dim3(D / 32, HD / 32, H), tb, 0, stream>>>(Wk, WQKVT + (size_t)D * D, HD, D, (long)D * HD, HD);
  transpose_f32_bf16<<<dim3(D / 32, HD / 32, H), tb, 0, stream>>>(Wv, WQKVT + (size_t)2 * D * D, HD, D, (long)D * HD, HD);
  transpose_f32_bf16<<<dim3(D / 32, D / 32, 1), tb, 0, stream>>>(Wp, WPT, D, D, 0, 0);
  transpose_f32_bf16<<<dim3(D / 32, F / 32, 1), tb, 0, stream>>>(W1, W1T, F, D, 0, 0);
  transpose_f32_bf16<<<dim3(F / 32, D / 32, 1), tb, 0, stream>>>(W2, W2T, D, F, 0, 0);
  // QKV projection (fused, N=6144): 16x24 = 384 blocks
  gemm8p<0, 256><<<dim3((S / 256) * (3 * D / 256)), 512, 0, stream>>>(
      XB, WQKVT, BQKV, nullptr, QKV, nullptr, S, 3 * D, D, 3 * D / 256);
  transpose_bf16<<<dim3(S / 32, D / 32), tb, 0, stream>>>(QKV, VT, 3 * D, S, 2 * D);
  attn_kernel<<<dim3(S / 128, H), 256, 0, stream>>>(QKV, VT, HEADS);
  // output projection + bias + residual -> fp32 pre-LN: 32x8 = 256 blocks (BM=128)
  gemm8p<1, 128><<<dim3((S / 128) * (D / 256)), 512, 0, stream>>>(
      HEADS, WPT, bp, x, nullptr, PRELN, S, D, D, D / 256);
  ln_kernel<<<S, 256, 0, stream>>>(PRELN, gamma, beta, Y);
  // FF1 (+bias, relu) -> bf16: 16x32 = 512 blocks
  gemm8p<2, 256><<<dim3((S / 256) * (F / 256)), 512, 0, stream>>>(
      Y, W1T, b1, nullptr, AB, nullptr, S, F, D, F / 256);
  // FF2 (+bias) -> fp32 out: 32x8 = 256 blocks (BM=128)
  gemm8p<3, 128><<<dim3((S / 128) * (D / 256)), 512, 0, stream>>>(
      AB, W2T, b2, nullptr, nullptr, OUT, S, D, F, D / 256);
}

// Round 4
// 914.973 us; speedup vs baseline: 1.1372x; 1.0451x over previous
//
#include <hip/hip_runtime.h>
#include <hip/hip_bf16.h>
#include <cstdint>
#include <cstddef>

#define S 4096
#define D 2048
#define H 16
#define HD 128
#define F 8192

typedef unsigned short ushort_t;
typedef __attribute__((ext_vector_type(8))) short short8;
typedef __attribute__((ext_vector_type(4))) float floatx4;

__device__ __forceinline__ ushort_t f2bf(float f) {
  union { float f; unsigned u; } v; v.f = f;
  unsigned u = v.u;
  return (ushort_t)((u + 0x7fffu + ((u >> 16) & 1u)) >> 16);
}

__device__ __forceinline__ void async16(void* lds, const void* g) {
  __builtin_amdgcn_global_load_lds(
      (const __attribute__((address_space(1))) unsigned int*)g,
      (__attribute__((address_space(3))) unsigned int*)lds, 16, 0, 0);
}

template <int N>
__device__ __forceinline__ void vmcnt_() {
  static_assert(N >= 0 && N <= 8, "vmcnt range");
  if constexpr (N == 0) asm volatile("s_waitcnt vmcnt(0)" ::: "memory");
  else if constexpr (N == 1) asm volatile("s_waitcnt vmcnt(1)" ::: "memory");
  else if constexpr (N == 2) asm volatile("s_waitcnt vmcnt(2)" ::: "memory");
  else if constexpr (N == 3) asm volatile("s_waitcnt vmcnt(3)" ::: "memory");
  else if constexpr (N == 4) asm volatile("s_waitcnt vmcnt(4)" ::: "memory");
  else if constexpr (N == 5) asm volatile("s_waitcnt vmcnt(5)" ::: "memory");
  else if constexpr (N == 6) asm volatile("s_waitcnt vmcnt(6)" ::: "memory");
  else if constexpr (N == 7) asm volatile("s_waitcnt vmcnt(7)" ::: "memory");
  else asm volatile("s_waitcnt vmcnt(8)" ::: "memory");
}
__device__ __forceinline__ void bar_() { asm volatile("s_barrier" ::: "memory"); }
__device__ __forceinline__ void lgkm0_() {
  asm volatile("s_waitcnt lgkmcnt(0)" ::: "memory");
  __builtin_amdgcn_sched_barrier(0);
}

// ---------------------------------------------------------------- prep kernels

__global__ void cast_bf16(const float* __restrict__ src, ushort_t* __restrict__ dst, int n4) {
  int i = blockIdx.x * blockDim.x + threadIdx.x;
  if (i < n4) {
    float4 v = ((const float4*)src)[i];
    ushort4 o;
    o.x = f2bf(v.x); o.y = f2bf(v.y); o.z = f2bf(v.z); o.w = f2bf(v.w);
    ((ushort4*)dst)[i] = o;
  }
}

__global__ void build_bqkv(const float* __restrict__ bq, const float* __restrict__ bk,
                           const float* __restrict__ bv, float* __restrict__ bqkv) {
  int n = blockIdx.x * blockDim.x + threadIdx.x;
  if (n < 3 * D) {
    float v;
    if (n < D) v = bq[n];
    else if (n < 2 * D) v = bk[n - D];
    else v = bv[n - 2 * D];
    bqkv[n] = v;
  }
}

// dst[c][r] = src[r][c]; fp32 in, bf16 out. block (32,8)
__global__ void transpose_f32_bf16(const float* __restrict__ src, ushort_t* __restrict__ dst,
                                   int ldS, int ldD, long srcBatchStride, long dstBatchRows) {
  __shared__ float t[32][33];
  int b = blockIdx.z;
  src += (size_t)b * srcBatchStride;
  dst += (size_t)b * dstBatchRows * ldD;
  int r0 = blockIdx.x * 32, c0 = blockIdx.y * 32;
  int tx = threadIdx.x, ty = threadIdx.y;
#pragma unroll
  for (int i = 0; i < 4; ++i)
    t[ty + i * 8][tx] = src[(size_t)(r0 + ty + i * 8) * ldS + c0 + tx];
  __syncthreads();
#pragma unroll
  for (int i = 0; i < 4; ++i)
    dst[(size_t)(c0 + ty + i * 8) * ldD + r0 + tx] = f2bf(t[tx][ty + i * 8]);
}

// bf16 transpose with column offset: dst[c][r] = src[r][colOff+c]. block (32,8)
__global__ void transpose_bf16(const ushort_t* __restrict__ src, ushort_t* __restrict__ dst,
                               int ldS, int ldD, int colOff) {
  __shared__ ushort_t t[32][33];
  int r0 = blockIdx.x * 32, c0 = blockIdx.y * 32;
  int tx = threadIdx.x, ty = threadIdx.y;
#pragma unroll
  for (int i = 0; i < 4; ++i)
    t[ty + i * 8][tx] = src[(size_t)(r0 + ty + i * 8) * ldS + colOff + c0 + tx];
  __syncthreads();
#pragma unroll
  for (int i = 0; i < 4; ++i)
    dst[(size_t)(c0 + ty + i * 8) * ldD + r0 + tx] = t[tx][ty + i * 8];
}

// ---------------------------------------------------------------- 4-phase GEMM
// C[M][N] = A[M][K] (bf16 rm) x Bt[N][K]^T (bf16 rm) + epilogue.
// Tile BM x 256, BK=64, 512 threads (8 waves), LDS double-buffer
// (even K-tile -> buf0, odd -> buf1; buffer indices compile-time).
// 4 phases per 2 K-tiles (2 per K-tile) -- merged from the 8-phase schedule
// after r3 counters showed barrier-pair sync cost dominating (MfmaUtil 29%):
// per phase = one A-half x BOTH B-halves = 2x MFMA per barrier-pair.
//   ph1: read buf0.{A0,B0,B1}; stage U.A1;          MFMA acc[0][0..1]
//   ph2: read buf0.A1; stage V.{A0,B0,B1}; MFMA acc[1][0..1]; vmcnt(LA+4)
//   ph3: read buf1.{A0,B0,B1}; stage V.A1;          MFMA acc[0][0..1]
//   ph4: read buf1.A1; stage W.{A0,B0,B1}; MFMA acc[1][0..1]; vmcnt(LA+4)
// (T=2i buf0, U=2i+1 buf1, V=2i+2 buf0, W=2i+3 buf1.)
// Ledger: every staged slot rewritten >=1 barrier after its last ds_read
// (A0/B0/B1 read ph1 -> staged ph2; A1 read ph2 -> staged ph3; mirrored);
// residency: prev ph4's vmcnt(LA+4) waits T.A1 -> T resident for ph1;
// ph2's vmcnt(LA+4) waits U.A1 -> U resident for ph3. Reads issued pre-bar#1
// complete at lgkm0 before bar#2, so next-phase stages cannot land early.
// HALF-ALIGNED fragment reads (load-bearing, r2 lesson): ldA(h) reads only
// rows of staged half h; ldB(h) only cols of staged half h.
// LDS rows (128B) XOR-swizzled both-sides: slot ^= row&7 on the pre-swizzled
// global source (linear global_load_lds dest) and on ds_read.
template <int MODE, int BM>
__global__ __launch_bounds__(512, 2)
void gemm8p(const ushort_t* __restrict__ A, const ushort_t* __restrict__ Bt,
            const float* __restrict__ bias, const float* __restrict__ resid,
            ushort_t* __restrict__ outb, float* __restrict__ outf,
            int M, int N, int K, int gridN) {
  constexpr int MQ = BM / 64;   // m-frags per wave per A-half
  constexpr int LA = BM / 128;  // loads/thread per A half-tile
  __shared__ __align__(16) ushort_t Abuf[2][BM * 64];
  __shared__ __align__(16) ushort_t Bbuf[2][256 * 64];

  const int tid = threadIdx.x;
  const int l = tid & 63, w = tid >> 6;
  const int c16 = l & 15, g = l >> 4;
  const int wm = w >> 2, wn = w & 3;

  // bijective XCD swizzle (m204); consecutive wgid share the A row-panel
  const int nwg = gridDim.x;
  const int q8 = nwg >> 3, r8 = nwg & 7;
  const int xcd = blockIdx.x & 7, bix = blockIdx.x >> 3;
  const int wgid = (xcd < r8 ? xcd * (q8 + 1) : r8 * (q8 + 1) + (xcd - r8) * q8) + bix;
  const int m0 = (wgid / gridN) * BM;
  const int n0 = (wgid % gridN) * 256;

  const size_t Kb = (size_t)K * 2;
  const size_t aHalfB = (size_t)(BM / 2) * Kb;
  const size_t bHalfB = (size_t)128 * Kb;

  // staging: chunk ch -> LDS bytes [ch*16, +16); content = global slot
  // (ch&7)^(row&7) of row ch>>3 (pre-swizzled source, linear dest).
  const char* aSrc[LA]; char* aLds[LA];
#pragma unroll
  for (int i = 0; i < LA; ++i) {
    int ch = i * 512 + tid;
    int row = ch >> 3;
    aSrc[i] = (const char*)A + (size_t)(m0 + row) * Kb + (((ch ^ row) & 7) << 4);
    aLds[i] = (char*)(&Abuf[0][0]) + ch * 16;
  }
  const char* bSrc[2]; char* bLds[2];
#pragma unroll
  for (int i = 0; i < 2; ++i) {
    int ch = i * 512 + tid;
    int row = ch >> 3;
    bSrc[i] = (const char*)Bt + (size_t)(n0 + row) * Kb + (((ch ^ row) & 7) << 4);
    bLds[i] = (char*)(&Bbuf[0][0]) + ch * 16;
  }

  auto stA = [&](int p, int h, int kByte) {
#pragma unroll
    for (int i = 0; i < LA; ++i)
      async16(aLds[i] + p * (BM * 128) + h * (BM * 64), aSrc[i] + (size_t)h * aHalfB + kByte);
  };
  auto stB = [&](int p, int h, int kByte) {
#pragma unroll
    for (int i = 0; i < 2; ++i)
      async16(bLds[i] + p * 32768 + h * 16384, bSrc[i] + (size_t)h * bHalfB + kByte);
  };

  // ds_read lane offsets: logical slot kk*4+g, swizzled by row&7 == c16&7
  int rdK[2];
  rdK[0] = ((g ^ (c16 & 7)) << 4);
  rdK[1] = (((4 + g) ^ (c16 & 7)) << 4);
  const char* Ab0 = (const char*)(&Abuf[0][0]);
  const char* Ab1 = Ab0 + BM * 128;
  const char* Bb0 = (const char*)(&Bbuf[0][0]);
  const char* Bb1 = Bb0 + 32768;

  floatx4 acc[2][2][MQ][2];  // [A-half][B-half][mf][nf]
#pragma unroll
  for (int ah = 0; ah < 2; ++ah)
#pragma unroll
    for (int bh = 0; bh < 2; ++bh)
#pragma unroll
      for (int mf = 0; mf < MQ; ++mf)
#pragma unroll
        for (int nf = 0; nf < 2; ++nf) acc[ah][bh][mf][nf] = (floatx4){0.f, 0.f, 0.f, 0.f};

  short8 af[MQ][2], bf0[2][2], bf1[2][2];
  // HALF-ALIGNED reads (see header comment).
  auto ldA = [&](const char* base, int h) {
#pragma unroll
    for (int mf = 0; mf < MQ; ++mf)
#pragma unroll
      for (int kk = 0; kk < 2; ++kk)
        af[mf][kk] = *(const short8*)(base + h * (BM * 64) +
            (wm * (BM / 4) + mf * 16 + c16) * 128 + rdK[kk]);
  };
  auto ldB = [&](const char* base, int h, short8 (&bf)[2][2]) {
#pragma unroll
    for (int nf = 0; nf < 2; ++nf)
#pragma unroll
      for (int kk = 0; kk < 2; ++kk)
        bf[nf][kk] = *(const short8*)(base + h * 16384 +
            (wn * 32 + nf * 16 + c16) * 128 + rdK[kk]);
  };
  // one phase's MFMA cluster: A-half ah x both B-halves (2*MQ*2*2 mfma)
  auto mma2 = [&](int ah) {
    __builtin_amdgcn_s_setprio(1);
#pragma unroll
    for (int mf = 0; mf < MQ; ++mf)
#pragma unroll
      for (int kk = 0; kk < 2; ++kk) {
#pragma unroll
        for (int nf = 0; nf < 2; ++nf)
          acc[ah][0][mf][nf] = __builtin_amdgcn_mfma_f32_16x16x32_bf16(
              af[mf][kk], bf0[nf][kk], acc[ah][0][mf][nf], 0, 0, 0);
#pragma unroll
        for (int nf = 0; nf < 2; ++nf)
          acc[ah][1][mf][nf] = __builtin_amdgcn_mfma_f32_16x16x32_bf16(
              af[mf][kk], bf1[nf][kk], acc[ah][1][mf][nf], 0, 0, 0);
      }
    __builtin_amdgcn_s_setprio(0);
  };

  // ---- prologue: T0 {A0,B0,B1,A1} + T1 {A0,B0,B1}; leave T1's 3 halves in flight
  stA(0, 0, 0); stB(0, 0, 0); stB(0, 1, 0); stA(0, 1, 0);
  stA(1, 0, 128); stB(1, 0, 128); stB(1, 1, 128);
  vmcnt_<LA + 4>();
  bar_();

  const int NI = K >> 7;  // iterations of 2 K-tiles
  for (int i = 0; i < NI; ++i) {
    const bool lastI = (i == NI - 1);
    const int kE = i << 8;  // even-tile K byte offset (tile 2i)

    // ph1: read buf0.{A0,B0,B1}; stage U.A1; MFMA acc[0][*]
    ldA(Ab0, 0); ldB(Bb0, 0, bf0); ldB(Bb0, 1, bf1);
    stA(1, 1, kE + 128);
    bar_(); lgkm0_();
    mma2(0);
    bar_();

    // ph2: read buf0.A1; stage V.{A0,B0,B1}; MFMA acc[1][*]; vmcnt -> U resident
    ldA(Ab0, 1);
    if (!lastI) { stA(0, 0, kE + 256); stB(0, 0, kE + 256); stB(0, 1, kE + 256); }
    bar_(); lgkm0_();
    mma2(1);
    if (lastI) vmcnt_<0>(); else vmcnt_<LA + 4>();
    bar_();

    // ph3: read buf1.{A0,B0,B1}; stage V.A1; MFMA acc[0][*]
    ldA(Ab1, 0); ldB(Bb1, 0, bf0); ldB(Bb1, 1, bf1);
    if (!lastI) stA(0, 1, kE + 256);
    bar_(); lgkm0_();
    mma2(0);
    bar_();

    // ph4: read buf1.A1; stage W.{A0,B0,B1}; MFMA acc[1][*]; vmcnt -> V resident
    ldA(Ab1, 1);
    if (!lastI) { stA(1, 0, kE + 384); stB(1, 0, kE + 384); stB(1, 1, kE + 384); }
    bar_(); lgkm0_();
    mma2(1);
    if (!lastI) { vmcnt_<LA + 4>(); bar_(); }
  }

  // ---- epilogue
#pragma unroll
  for (int ah = 0; ah < 2; ++ah)
#pragma unroll
    for (int bh = 0; bh < 2; ++bh)
#pragma unroll
      for (int nf = 0; nf < 2; ++nf) {
        int gcol = n0 + bh * 128 + wn * 32 + nf * 16 + c16;
        float bj = bias[gcol];
#pragma unroll
        for (int mf = 0; mf < MQ; ++mf) {
          int grow = m0 + ah * (BM / 2) + wm * (BM / 4) + mf * 16 + g * 4;
#pragma unroll
          for (int r = 0; r < 4; ++r) {
            float v = acc[ah][bh][mf][nf][r] + bj;
            size_t o = (size_t)(grow + r) * N + gcol;
            if (MODE == 0) {
              outb[o] = f2bf(v);
            } else if (MODE == 1) {
              outf[o] = v + resid[o];
            } else if (MODE == 2) {
              outb[o] = f2bf(v > 0.f ? v : 0.f);
            } else {
              outf[o] = v;
            }
          }
        }
      }
}

// ---------------------------------------------------------------- flash attention (v3)
__global__ __launch_bounds__(256, 2)
void attn_kernel(const ushort_t* __restrict__ QKV, const ushort_t* __restrict__ Vt,
                 ushort_t* __restrict__ heads) {
  const int h = blockIdx.y;
  const int tid = threadIdx.x, w = tid >> 6, l = tid & 63;
  const int g = l >> 4, c = l & 15;
  const int q0 = blockIdx.x * 128 + w * 32;
  const float scale = 0.08838834764831845f;  // 1/sqrt(128)

  __shared__ __align__(16) ushort_t Ks[64 * 128];   // [t][d] rows 256B, chunk-swizzled
  __shared__ __align__(16) ushort_t Vs[128 * 64];   // [e][t] rows 128B, chunk-swizzled
  __shared__ __align__(16) ushort_t Ps[4][2][16][72];  // wave-private P, pad-72

  short8 qf[2][4];
#pragma unroll
  for (int u = 0; u < 2; ++u)
#pragma unroll
    for (int k0 = 0; k0 < 4; ++k0)
      qf[u][k0] = *(const short8*)(QKV + (size_t)(q0 + u * 16 + c) * (3 * D) + h * HD + k0 * 32 + g * 8);

  floatx4 o[2][8];
#pragma unroll
  for (int u = 0; u < 2; ++u)
#pragma unroll
    for (int j = 0; j < 8; ++j) o[u][j] = (floatx4){0.f, 0.f, 0.f, 0.f};
  float l_run[2] = {0.f, 0.f};

  for (int t0 = 0; t0 < S; t0 += 64) {
#pragma unroll
    for (int cc = 0; cc < 4; ++cc) {
      int slot = cc * 256 + tid;
      int krow = slot >> 4, kch = slot & 15;
      const char* gk = (const char*)QKV +
          ((size_t)(t0 + krow) * (3 * D) + D + h * HD) * 2 + ((kch ^ (krow & 15)) << 4);
      async16((char*)Ks + (size_t)(cc * 256 + w * 64) * 16, gk);
      int vrow = slot >> 3, vch = slot & 7;
      const char* gv = (const char*)Vt +
          ((size_t)(h * HD + vrow) * S + t0) * 2 + ((vch ^ (vrow & 7)) << 4);
      async16((char*)Vs + (size_t)(cc * 256 + w * 64) * 16, gv);
    }
    __syncthreads();

    floatx4 sc[2][4];
#pragma unroll
    for (int u = 0; u < 2; ++u)
#pragma unroll
      for (int tt = 0; tt < 4; ++tt) sc[u][tt] = (floatx4){0.f, 0.f, 0.f, 0.f};
#pragma unroll
    for (int tt = 0; tt < 4; ++tt) {
      short8 kf[4];
#pragma unroll
      for (int k0 = 0; k0 < 4; ++k0)
        kf[k0] = *(const short8*)(Ks + (tt * 16 + c) * 128 + (((k0 * 4 + g) ^ c) << 3));
#pragma unroll
      for (int u = 0; u < 2; ++u)
#pragma unroll
        for (int k0 = 0; k0 < 4; ++k0)
          sc[u][tt] = __builtin_amdgcn_mfma_f32_16x16x32_bf16(kf[k0], qf[u][k0], sc[u][tt], 0, 0, 0);
    }

#pragma unroll
    for (int u = 0; u < 2; ++u) {
#pragma unroll
      for (int tt = 0; tt < 4; ++tt) {
        float p0 = __expf(sc[u][tt][0] * scale);
        float p1 = __expf(sc[u][tt][1] * scale);
        float p2 = __expf(sc[u][tt][2] * scale);
        float p3 = __expf(sc[u][tt][3] * scale);
        l_run[u] += p0 + p1 + p2 + p3;
        ushort4 pk;
        pk.x = f2bf(p0); pk.y = f2bf(p1); pk.z = f2bf(p2); pk.w = f2bf(p3);
        *reinterpret_cast<ushort4*>(&Ps[w][u][c][tt * 16 + g * 4]) = pk;
      }
    }
    __asm__ volatile("s_waitcnt lgkmcnt(0)" ::: "memory");

    short8 pf[2][2];
#pragma unroll
    for (int u = 0; u < 2; ++u)
#pragma unroll
      for (int tk = 0; tk < 2; ++tk)
        pf[u][tk] = *reinterpret_cast<const short8*>(&Ps[w][u][c][tk * 32 + g * 8]);
#pragma unroll
    for (int j = 0; j < 8; ++j) {
#pragma unroll
      for (int tk = 0; tk < 2; ++tk) {
        short8 vf = *(const short8*)(Vs + (j * 16 + c) * 64 + (((tk * 4 + g) ^ (c & 7)) << 3));
#pragma unroll
        for (int u = 0; u < 2; ++u)
          o[u][j] = __builtin_amdgcn_mfma_f32_16x16x32_bf16(pf[u][tk], vf, o[u][j], 0, 0, 0);
      }
    }
    __syncthreads();
  }

#pragma unroll
  for (int u = 0; u < 2; ++u) {
    float lt = l_run[u];
    lt += __shfl_xor(lt, 16);
    lt += __shfl_xor(lt, 32);
    float linv[4];
#pragma unroll
    for (int r = 0; r < 4; ++r) linv[r] = 1.f / __shfl(lt, g * 4 + r);
    ushort_t* hp = heads + (size_t)(q0 + u * 16 + g * 4) * D + h * HD + c;
#pragma unroll
    for (int j = 0; j < 8; ++j)
#pragma unroll
      for (int r = 0; r < 4; ++r)
        hp[(size_t)r * D + j * 16] = f2bf(o[u][j][r] * linv[r]);
  }
}

// ---------------------------------------------------------------- LayerNorm
__global__ __launch_bounds__(256)
void ln_kernel(const float* __restrict__ preln, const float* __restrict__ gamma,
               const float* __restrict__ beta, ushort_t* __restrict__ y) {
  int row = blockIdx.x, tid = threadIdx.x;
  const float* p = preln + (size_t)row * D;
  float vals[8];
  float sum = 0.f, ss = 0.f;
#pragma unroll
  for (int k = 0; k < 8; ++k) {
    float v = p[tid + k * 256];
    vals[k] = v; sum += v; ss += v * v;
  }
#pragma unroll
  for (int off = 32; off >= 1; off >>= 1) {
    sum += __shfl_xor(sum, off);
    ss += __shfl_xor(ss, off);
  }
  __shared__ float s1[4], s2[4];
  int w = tid >> 6, l = tid & 63;
  if (l == 0) { s1[w] = sum; s2[w] = ss; }
  __syncthreads();
  sum = s1[0] + s1[1] + s1[2] + s1[3];
  ss = s2[0] + s2[1] + s2[2] + s2[3];
  float mu = sum / (float)D;
  float var = ss / (float)D - mu * mu;
  float rs = rsqrtf(var + 1e-5f);
  ushort_t* yr = y + (size_t)row * D;
#pragma unroll
  for (int k = 0; k < 8; ++k) {
    int d = tid + k * 256;
    yr[d] = f2bf((vals[k] - mu) * rs * gamma[d] + beta[d]);
  }
}

// ---------------------------------------------------------------- launch

extern "C" void kernel_launch(void* const* d_in, const int* in_sizes, int n_in,
                              void* d_out, int out_size, void* d_ws, size_t ws_size,
                              hipStream_t stream) {
  const float* x = (const float*)d_in[0];
  const float* Wq = (const float*)d_in[1];
  const float* bq = (const float*)d_in[2];
  const float* Wk = (const float*)d_in[3];
  const float* bk = (const float*)d_in[4];
  const float* Wv = (const float*)d_in[5];
  const float* bv = (const float*)d_in[6];
  const float* Wp = (const float*)d_in[7];
  const float* bp = (const float*)d_in[8];
  const float* W1 = (const float*)d_in[9];
  const float* b1 = (const float*)d_in[10];
  const float* W2 = (const float*)d_in[11];
  const float* b2 = (const float*)d_in[12];
  const float* gamma = (const float*)d_in[13];
  const float* beta = (const float*)d_in[14];

  char* ws = (char*)d_ws;
  ushort_t* WQKVT = (ushort_t*)(ws + 0);          // 25,165,824  [dead after QKV gemm]
  ushort_t* XB    = (ushort_t*)(ws + 25165824);   // 16,777,216  [dead after QKV gemm]
  float*    BQKV  = (float*)(ws + 41943040);      //     24,576
  ushort_t* WPT   = (ushort_t*)(ws + 41975808);   //  8,388,608
  ushort_t* W1T   = (ushort_t*)(ws + 50364416);   // 33,554,432
  ushort_t* W2T   = (ushort_t*)(ws + 83918848);   // 33,554,432
  ushort_t* QKV   = (ushort_t*)(ws + 117473280);  // 50,331,648  [dead after attn]
  ushort_t* HEADS = (ushort_t*)(ws + 167804928);  // 16,777,216  [dead after proj]
  ushort_t* VT    = (ushort_t*)(ws + 184582144);  // 16,777,216  [dead after attn]
  float*    PRELN = (float*)(ws + 0);             // 33,554,432 over WQKVT+XB
  ushort_t* AB    = (ushort_t*)(ws + 117473280);  // 67,108,864 over QKV+HEADS
  ushort_t* Y     = (ushort_t*)(ws + 184582144);  // 16,777,216 over VT
  float* OUT = (float*)d_out;

  dim3 tb(32, 8);
  cast_bf16<<<(S * D / 4 + 255) / 256, 256, 0, stream>>>(x, XB, S * D / 4);
  build_bqkv<<<(3 * D + 255) / 256, 256, 0, stream>>>(bq, bk, bv, BQKV);
  transpose_f32_bf16<<<dim3(D / 32, HD / 32, H), tb, 0, stream>>>(Wq, WQKVT, HD, D, (long)D * HD, HD);
  transpose_f32_bf16<<<dim3(D / 32, HD / 32, H), tb, 0, stream>>>(Wk, WQKVT + (size_t)D * D, HD, D, (long)D * HD, HD);
  transpose_f32_bf16<<<dim3(D / 32, HD / 32, H), tb, 0, stream>>>(Wv, WQKVT + (size_t)2 * D * D, HD, D, (long)D * HD, HD);
  transpose_f32_bf16<<<dim3(D / 32, D / 32, 1), tb, 0, stream>>>(Wp, WPT, D, D, 0, 0);
  transpose_f32_bf16<<<dim3(D / 32, F / 32, 1), tb, 0, stream>>>(W1, W1T, F, D, 0, 0);
  transpose_f32_bf16<<<dim3(F / 32, D / 32, 1), tb, 0, stream>>>(W2, W2T, D, F, 0, 0);
  // QKV projection (fused, N=6144): 16x24 = 384 blocks
  gemm8p<0, 256><<<dim3((S / 256) * (3 * D / 256)), 512, 0, stream>>>(
      XB, WQKVT, BQKV, nullptr, QKV, nullptr, S, 3 * D, D, 3 * D / 256);
  transpose_bf16<<<dim3(S / 32, D / 32), tb, 0, stream>>>(QKV, VT, 3 * D, S, 2 * D);
  attn_kernel<<<dim3(S / 128, H), 256, 0, stream>>>(QKV, VT, HEADS);
  // output projection + bias + residual -> fp32 pre-LN: 32x8 = 256 blocks (BM=128)
  gemm8p<1, 128><<<dim3((S / 128) * (D / 256)), 512, 0, stream>>>(
      HEADS, WPT, bp, x, nullptr, PRELN, S, D, D, D / 256);
  ln_kernel<<<S, 256, 0, stream>>>(PRELN, gamma, beta, Y);
  // FF1 (+bias, relu) -> bf16: 16x32 = 512 blocks
  gemm8p<2, 256><<<dim3((S / 256) * (F / 256)), 512, 0, stream>>>(
      Y, W1T, b1, nullptr, AB, nullptr, S, F, D, F / 256);
  // FF2 (+bias) -> fp32 out: 32x8 = 256 blocks (BM=128)
  gemm8p<3, 128><<<dim3((S / 128) * (D / 256)), 512, 0, stream>>>(
      AB, W2T, b2, nullptr, nullptr, OUT, S, D, F, D / 256);
}